// Round 2
// baseline (7550.165 us; speedup 1.0000x reference)
//
#include <hip/hip_runtime.h>

#define N_NODES 100000
#define IN_CH 32
#define EDGE_CH 16
#define OUT_CH 32
#define D_CAT 80   // 2*IN_CH + EDGE_CH
#define D_MID 56

// Order-preserving float->uint encoding: float compare == uint compare.
// enc(-inf) = ~0xFF800000 = 0x007FFFFF
#define ENC_NEGINF 0x007FFFFFu

__device__ __forceinline__ unsigned fenc(float f) {
    unsigned u = __float_as_uint(f);
    return (u & 0x80000000u) ? ~u : (u | 0x80000000u);
}
__device__ __forceinline__ float fdec(unsigned u) {
    u = (u & 0x80000000u) ? (u ^ 0x80000000u) : ~u;
    return __uint_as_float(u);
}

// round-to-nearest-even onto the bf16 grid, result as f32
__device__ __forceinline__ float bfr(float f) {
    unsigned u = __float_as_uint(f);
    u = (u + 0x7FFFu + ((u >> 16) & 1u)) & 0xFFFF0000u;
    return __uint_as_float(u);
}

__global__ void init_agg(unsigned* __restrict__ agg, int n4) {
    int i = blockIdx.x * blockDim.x + threadIdx.x;
    if (i < n4) {
        ((uint4*)agg)[i] = make_uint4(ENC_NEGINF, ENC_NEGINF, ENC_NEGINF, ENC_NEGINF);
    }
}

__global__ __launch_bounds__(256) void edge_mlp(
    const float* __restrict__ x, const int* __restrict__ ei,
    const float* __restrict__ ea, const float* __restrict__ W1,
    const float* __restrict__ b1, const float* __restrict__ W2,
    const float* __restrict__ b2, unsigned* __restrict__ agg, int nE)
{
    __shared__ float sW1[D_CAT * D_MID];   // 17920 B
    __shared__ float sW2[D_MID * OUT_CH];  //  7168 B
    __shared__ float sb1[D_MID];
    __shared__ float sb2[OUT_CH];
    for (int i = threadIdx.x; i < D_CAT * D_MID; i += 256) sW1[i] = bfr(W1[i]);
    for (int i = threadIdx.x; i < D_MID * OUT_CH; i += 256) sW2[i] = bfr(W2[i]);
    if (threadIdx.x < D_MID) sb1[threadIdx.x] = bfr(b1[threadIdx.x]);
    if (threadIdx.x < OUT_CH) sb2[threadIdx.x] = bfr(b2[threadIdx.x]);
    __syncthreads();

    int e = blockIdx.x * 256 + threadIdx.x;
    if (e >= nE) return;
    int r = ei[e];          // source node (x[rol])
    int c = ei[nE + e];     // destination node (x[col], also scatter target)
    if ((unsigned)r >= N_NODES || (unsigned)c >= N_NODES) return;  // safety vs UB

    float h[D_MID];
#pragma unroll
    for (int j = 0; j < D_MID; ++j) h[j] = sb1[j];

    const float4* xr = (const float4*)(x + (size_t)r * IN_CH);
    const float4* xc = (const float4*)(x + (size_t)c * IN_CH);
    const float4* ep = (const float4*)(ea + (size_t)e * EDGE_CH);

    // h += x[r] rows of W1  (rows 0..31)
    for (int blk = 0; blk < IN_CH / 4; ++blk) {
        float4 in4 = xr[blk];
        const float* w = &sW1[(blk * 4) * D_MID];
#pragma unroll
        for (int ii = 0; ii < 4; ++ii) {
            float vi = bfr((&in4.x)[ii]);
#pragma unroll
            for (int j = 0; j < D_MID; ++j) h[j] += vi * w[ii * D_MID + j];
        }
    }
    // h += x[c] rows of W1  (rows 32..63)
    for (int blk = 0; blk < IN_CH / 4; ++blk) {
        float4 in4 = xc[blk];
        const float* w = &sW1[(IN_CH + blk * 4) * D_MID];
#pragma unroll
        for (int ii = 0; ii < 4; ++ii) {
            float vi = bfr((&in4.x)[ii]);
#pragma unroll
            for (int j = 0; j < D_MID; ++j) h[j] += vi * w[ii * D_MID + j];
        }
    }
    // h += edge_attr rows of W1 (rows 64..79)
    for (int blk = 0; blk < EDGE_CH / 4; ++blk) {
        float4 in4 = ep[blk];
        const float* w = &sW1[(2 * IN_CH + blk * 4) * D_MID];
#pragma unroll
        for (int ii = 0; ii < 4; ++ii) {
            float vi = bfr((&in4.x)[ii]);
#pragma unroll
            for (int j = 0; j < D_MID; ++j) h[j] += vi * w[ii * D_MID + j];
        }
    }

    // second layer: v = leaky(h)@W2 + b2, with h rounded to bf16 (ref stores h as bf16)
    float v[OUT_CH];
#pragma unroll
    for (int j = 0; j < OUT_CH; ++j) v[j] = sb2[j];
#pragma unroll
    for (int i = 0; i < D_MID; ++i) {
        float hv = h[i];
        hv = (hv > 0.f) ? hv : 0.01f * hv;
        hv = bfr(hv);
#pragma unroll
        for (int j = 0; j < OUT_CH; ++j) v[j] += hv * sW2[i * OUT_CH + j];
    }

    // scatter-max into agg[c], read-filtered to cut atomic traffic.
    unsigned* arow = agg + (size_t)c * OUT_CH;
#pragma unroll
    for (int q = 0; q < OUT_CH / 4; ++q) {
        uint4 cur4 = ((const uint4*)arow)[q];
        unsigned cu[4] = {cur4.x, cur4.y, cur4.z, cur4.w};
#pragma unroll
        for (int k = 0; k < 4; ++k) {
            float vo = v[q * 4 + k];
            vo = (vo > 0.f) ? vo : 0.01f * vo;   // leaky after layer 2
            vo = bfr(vo);                        // ref stores v as bf16
            unsigned ev = fenc(vo);
            if (ev > cu[k]) atomicMax(arow + q * 4 + k, ev);
        }
    }
}

// out[n][c] = max( (agg empty ? 0 : agg), bf16(x[n][c]) )   (IN_CH==OUT_CH)
__global__ void finalize_kernel(const float* __restrict__ x, unsigned* __restrict__ aggout, int n4) {
    int i = blockIdx.x * blockDim.x + threadIdx.x;
    if (i >= n4) return;
    uint4 u = ((const uint4*)aggout)[i];
    float4 xv = ((const float4*)x)[i];
    float4 o;
    o.x = fmaxf((u.x == ENC_NEGINF) ? 0.f : fdec(u.x), bfr(xv.x));
    o.y = fmaxf((u.y == ENC_NEGINF) ? 0.f : fdec(u.y), bfr(xv.y));
    o.z = fmaxf((u.z == ENC_NEGINF) ? 0.f : fdec(u.z), bfr(xv.z));
    o.w = fmaxf((u.w == ENC_NEGINF) ? 0.f : fdec(u.w), bfr(xv.w));
    ((float4*)aggout)[i] = o;
}

extern "C" void kernel_launch(void* const* d_in, const int* in_sizes, int n_in,
                              void* d_out, int out_size, void* d_ws, size_t ws_size,
                              hipStream_t stream) {
    const float* x  = (const float*)d_in[0];
    const int*   ei = (const int*)d_in[1];
    const float* ea = (const float*)d_in[2];
    const float* W1 = (const float*)d_in[3];
    const float* b1 = (const float*)d_in[4];
    const float* W2 = (const float*)d_in[5];
    const float* b2 = (const float*)d_in[6];
    unsigned* agg = (unsigned*)d_out;   // aggregation buffer lives in d_out (encoded)

    const int nE = in_sizes[1] / 2;     // 1,000,000
    const int n  = out_size;            // 100000*32 = 3,200,000
    const int n4 = n / 4;

    init_agg<<<(n4 + 255) / 256, 256, 0, stream>>>(agg, n4);
    edge_mlp<<<(nE + 255) / 256, 256, 0, stream>>>(x, ei, ea, W1, b1, W2, b2, agg, nE);
    finalize_kernel<<<(n4 + 255) / 256, 256, 0, stream>>>(x, agg, n4);
}

// Round 3
// 310.281 us; speedup vs baseline: 24.3333x; 24.3333x over previous
//
#include <hip/hip_runtime.h>

#define N_NODES 100000
#define IN_CH 32
#define EDGE_CH 16
#define OUT_CH 32
#define D_CAT 80   // 2*IN_CH + EDGE_CH
#define D_MID 56

// LDS row strides (elements) chosen so row stride in dwords is ~odd -> <=2-way bank aliasing
#define FEAT_LD 104   // 96 cols + 8 pad
#define W1T_LD 104
#define H_LD 72       // 64 cols + 8 pad
#define W2T_LD 72

#define ENC_NEGINF 0x007FFFFFu

typedef short short8 __attribute__((ext_vector_type(8)));
typedef float f32x4 __attribute__((ext_vector_type(4)));

__device__ __forceinline__ unsigned fenc(float f) {
    unsigned u = __float_as_uint(f);
    return (u & 0x80000000u) ? ~u : (u | 0x80000000u);
}
__device__ __forceinline__ float fdec(unsigned u) {
    u = (u & 0x80000000u) ? (u ^ 0x80000000u) : ~u;
    return __uint_as_float(u);
}
// RNE to bf16 grid, as f32
__device__ __forceinline__ float bfr(float f) {
    unsigned u = __float_as_uint(f);
    u = (u + 0x7FFFu + ((u >> 16) & 1u)) & 0xFFFF0000u;
    return __uint_as_float(u);
}
// RNE to bf16 bits
__device__ __forceinline__ unsigned short bf16b(float f) {
    unsigned u = __float_as_uint(f);
    return (unsigned short)((u + 0x7FFFu + ((u >> 16) & 1u)) >> 16);
}

// ---- prep: transpose+pad weights to bf16 in ws, biases as bf16-grid f32 ----
__global__ void prep_weights(const float* __restrict__ W1, const float* __restrict__ b1,
                             const float* __restrict__ W2, const float* __restrict__ b2,
                             unsigned short* __restrict__ wsW1T, unsigned short* __restrict__ wsW2T,
                             float* __restrict__ wsb1, float* __restrict__ wsb2) {
    int t = threadIdx.x;
    // W1T[n][k] over [64][96], zero-padded (real: n<56, k<80). W1 is [80][56].
    for (int s = t; s < 64 * 96; s += 256) {
        int n = s / 96, k = s % 96;
        wsW1T[s] = (n < D_MID && k < D_CAT) ? bf16b(W1[k * D_MID + n]) : (unsigned short)0;
    }
    // W2T[n][k] over [32][64], zero-padded (real: k<56). W2 is [56][32].
    for (int s = t; s < 32 * 64; s += 256) {
        int n = s / 64, k = s % 64;
        wsW2T[s] = (k < D_MID) ? bf16b(W2[k * OUT_CH + n]) : (unsigned short)0;
    }
    if (t < 64) wsb1[t] = (t < D_MID) ? bfr(b1[t]) : 0.f;
    if (t < 32) wsb2[t] = bfr(b2[t]);
}

__global__ void init_agg(unsigned* __restrict__ agg, int n4) {
    int i = blockIdx.x * blockDim.x + threadIdx.x;
    if (i < n4)
        ((uint4*)agg)[i] = make_uint4(ENC_NEGINF, ENC_NEGINF, ENC_NEGINF, ENC_NEGINF);
}

// ---- fused gather + MLP (MFMA) + scatter-max, 64 edges per block ----
__global__ __launch_bounds__(256) void edge_mlp_mfma(
    const float* __restrict__ x, const int* __restrict__ ei, const float* __restrict__ ea,
    const unsigned short* __restrict__ wsW1T, const unsigned short* __restrict__ wsW2T,
    const float* __restrict__ wsb1, const float* __restrict__ wsb2,
    unsigned* __restrict__ agg, int nE)
{
    __shared__ unsigned short sFeat[64 * FEAT_LD];  // 13312 B
    __shared__ unsigned short sW1T[64 * W1T_LD];    // 13312 B
    __shared__ unsigned short sH[64 * H_LD];        //  9216 B
    __shared__ unsigned short sW2T[32 * W2T_LD];    //  4608 B
    __shared__ float sb1f[64];
    __shared__ float sb2f[32];
    __shared__ int sdst[64];

    const int t = threadIdx.x;
    const int e0 = blockIdx.x * 64;

    // --- stage weights (coalesced short8 from ws, padded rows in LDS) ---
    for (int s = t; s < 64 * 96 / 8; s += 256) {      // 768 chunks
        int n = s / 12, kc = s % 12;
        *(short8*)&sW1T[n * W1T_LD + kc * 8] = *(const short8*)(wsW1T + s * 8);
    }
    {   // 256 chunks
        int n = t >> 3, kc = t & 7;
        *(short8*)&sW2T[n * W2T_LD + kc * 8] = *(const short8*)(wsW2T + t * 8);
    }
    if (t < 64) sb1f[t] = wsb1[t];
    else if (t < 96) sb2f[t - 64] = wsb2[t - 64];

    // --- stage gathered features as bf16 ---
    {
        int edge = t >> 2, q = t & 3;
        int e = e0 + edge;
        bool ok = e < nE;
        int src = ok ? ei[e] : 0;
        int dst = ok ? ei[nE + e] : -1;
        if (q == 0) sdst[edge] = dst;
        if ((unsigned)src >= N_NODES) src = 0;
        int dsts = ((unsigned)dst < N_NODES) ? dst : 0;

        // x[src] -> cols 0..31 (this thread: q*8..q*8+7)
        {
            float4 a = ok ? ((const float4*)(x + (size_t)src * IN_CH))[q * 2]     : make_float4(0,0,0,0);
            float4 b = ok ? ((const float4*)(x + (size_t)src * IN_CH))[q * 2 + 1] : make_float4(0,0,0,0);
            short8 p = { (short)bf16b(a.x), (short)bf16b(a.y), (short)bf16b(a.z), (short)bf16b(a.w),
                         (short)bf16b(b.x), (short)bf16b(b.y), (short)bf16b(b.z), (short)bf16b(b.w) };
            *(short8*)&sFeat[edge * FEAT_LD + q * 8] = p;
        }
        // x[dst] -> cols 32..63
        {
            float4 a = ok ? ((const float4*)(x + (size_t)dsts * IN_CH))[q * 2]     : make_float4(0,0,0,0);
            float4 b = ok ? ((const float4*)(x + (size_t)dsts * IN_CH))[q * 2 + 1] : make_float4(0,0,0,0);
            short8 p = { (short)bf16b(a.x), (short)bf16b(a.y), (short)bf16b(a.z), (short)bf16b(a.w),
                         (short)bf16b(b.x), (short)bf16b(b.y), (short)bf16b(b.z), (short)bf16b(b.w) };
            *(short8*)&sFeat[edge * FEAT_LD + 32 + q * 8] = p;
        }
        // ea -> cols 64..79 (this thread: 64+q*4 .. +3); zeros -> cols 80..95 (80+q*4)
        {
            float4 a = ok ? ((const float4*)(ea + (size_t)e * EDGE_CH))[q] : make_float4(0,0,0,0);
            unsigned short* fp = &sFeat[edge * FEAT_LD + 64 + q * 4];
            fp[0] = bf16b(a.x); fp[1] = bf16b(a.y); fp[2] = bf16b(a.z); fp[3] = bf16b(a.w);
            *(uint2*)&sFeat[edge * FEAT_LD + 80 + q * 4] = make_uint2(0u, 0u);
        }
    }
    __syncthreads();

    const int wave = t >> 6;
    const int l15  = t & 15;
    const int quad = (t & 63) >> 4;
    const int wm   = wave * 16;   // this wave's M-tile base (edge row)

    // --- GEMM1: feat[64x96] @ W1T -> h[64x64(56 real)] ---
    f32x4 acc[4];
#pragma unroll
    for (int nt = 0; nt < 4; ++nt) acc[nt] = (f32x4){0.f, 0.f, 0.f, 0.f};
#pragma unroll
    for (int ks = 0; ks < 3; ++ks) {
        short8 a = *(const short8*)&sFeat[(wm + l15) * FEAT_LD + ks * 32 + quad * 8];
#pragma unroll
        for (int nt = 0; nt < 4; ++nt) {
            short8 b = *(const short8*)&sW1T[(nt * 16 + l15) * W1T_LD + ks * 32 + quad * 8];
            acc[nt] = __builtin_amdgcn_mfma_f32_16x16x32_bf16(a, b, acc[nt], 0, 0, 0);
        }
    }
    // bias + leaky + bf16, store to sH (C-layout -> A-layout via LDS)
#pragma unroll
    for (int nt = 0; nt < 4; ++nt) {
        int col = nt * 16 + l15;
        float bias = sb1f[col];
#pragma unroll
        for (int j = 0; j < 4; ++j) {
            int row = wm + quad * 4 + j;
            float v = acc[nt][j] + bias;
            v = (v > 0.f) ? v : 0.01f * v;
            sH[row * H_LD + col] = (col < D_MID) ? bf16b(v) : (unsigned short)0;
        }
    }
    __syncthreads();

    // --- GEMM2: h[64x64] @ W2T -> v[64x32] ---
    f32x4 acc2[2];
#pragma unroll
    for (int nt = 0; nt < 2; ++nt) acc2[nt] = (f32x4){0.f, 0.f, 0.f, 0.f};
#pragma unroll
    for (int ks = 0; ks < 2; ++ks) {
        short8 a = *(const short8*)&sH[(wm + l15) * H_LD + ks * 32 + quad * 8];
#pragma unroll
        for (int nt = 0; nt < 2; ++nt) {
            short8 b = *(const short8*)&sW2T[(nt * 16 + l15) * W2T_LD + ks * 32 + quad * 8];
            acc2[nt] = __builtin_amdgcn_mfma_f32_16x16x32_bf16(a, b, acc2[nt], 0, 0, 0);
        }
    }
    // bias + leaky + bf16 + encoded filtered scatter-max
#pragma unroll
    for (int nt = 0; nt < 2; ++nt) {
        int col = nt * 16 + l15;
        float bias = sb2f[col];
#pragma unroll
        for (int j = 0; j < 4; ++j) {
            int m = quad * 4 + j;
            int dst = sdst[wm + m];
            if ((unsigned)dst >= N_NODES) continue;
            float v = acc2[nt][j] + bias;
            v = (v > 0.f) ? v : 0.01f * v;
            unsigned ev = fenc(bfr(v));
            unsigned* p = agg + (size_t)dst * OUT_CH + col;
            unsigned cur = *p;                 // monotone filter (stale read only underestimates)
            if (ev > cur) atomicMax(p, ev);
        }
    }
}

// out[n][c] = max( (agg empty ? 0 : agg), bf16(x[n][c]) )   (IN_CH==OUT_CH)
__global__ void finalize_kernel(const float* __restrict__ x, unsigned* __restrict__ aggout, int n4) {
    int i = blockIdx.x * blockDim.x + threadIdx.x;
    if (i >= n4) return;
    uint4 u = ((const uint4*)aggout)[i];
    float4 xv = ((const float4*)x)[i];
    float4 o;
    o.x = fmaxf((u.x == ENC_NEGINF) ? 0.f : fdec(u.x), bfr(xv.x));
    o.y = fmaxf((u.y == ENC_NEGINF) ? 0.f : fdec(u.y), bfr(xv.y));
    o.z = fmaxf((u.z == ENC_NEGINF) ? 0.f : fdec(u.z), bfr(xv.z));
    o.w = fmaxf((u.w == ENC_NEGINF) ? 0.f : fdec(u.w), bfr(xv.w));
    ((float4*)aggout)[i] = o;
}

extern "C" void kernel_launch(void* const* d_in, const int* in_sizes, int n_in,
                              void* d_out, int out_size, void* d_ws, size_t ws_size,
                              hipStream_t stream) {
    const float* x  = (const float*)d_in[0];
    const int*   ei = (const int*)d_in[1];
    const float* ea = (const float*)d_in[2];
    const float* W1 = (const float*)d_in[3];
    const float* b1 = (const float*)d_in[4];
    const float* W2 = (const float*)d_in[5];
    const float* b2 = (const float*)d_in[6];
    unsigned* agg = (unsigned*)d_out;

    // ws carve-up: W1T 6144 sh | W2T 2048 sh | b1 64 f | b2 32 f  (~16.8 KB)
    unsigned short* wsW1T = (unsigned short*)d_ws;
    unsigned short* wsW2T = wsW1T + 64 * 96;
    float* wsb1 = (float*)(wsW2T + 32 * 64);
    float* wsb2 = wsb1 + 64;

    const int nE = in_sizes[1] / 2;     // 1,000,000
    const int n  = out_size;            // 3,200,000
    const int n4 = n / 4;

    prep_weights<<<1, 256, 0, stream>>>(W1, b1, W2, b2, wsW1T, wsW2T, wsb1, wsb2);
    init_agg<<<(n4 + 255) / 256, 256, 0, stream>>>(agg, n4);
    edge_mlp_mfma<<<(nE + 63) / 64, 256, 0, stream>>>(x, ei, ea, wsW1T, wsW2T, wsb1, wsb2, agg, nE);
    finalize_kernel<<<(n4 + 255) / 256, 256, 0, stream>>>(x, agg, n4);
}